// Round 1
// baseline (474.102 us; speedup 1.0000x reference)
//
#include <hip/hip_runtime.h>

// Problem constants (fixed by setup_inputs: B=16, H=W=1024, k=9 -> R=4)
#define HH 1024
#define WW 1024
#define BB 16
#define RR 4
#define TY 32
#define TX 64
#define LW (TX + 8)            // LDS row width (72 floats)
#define DMAXC 15.0f
#define ENHC 2.0f
#define NEGWC 1.5f
#define EGFC 10.0f

__device__ __forceinline__ void fma4(float4& a, float c, const float4& v) {
    a.x += c * v.x; a.y += c * v.y; a.z += c * v.z; a.w += c * v.w;
}

// horizontal 9-tap conv producing 4 consecutive outputs from 12-value window
__device__ __forceinline__ float4 hconv(const float* __restrict__ row, int xg,
                                        const float (&cf)[9]) {
    float w[12];
    *(float4*)&w[0] = *(const float4*)&row[xg];
    *(float4*)&w[4] = *(const float4*)&row[xg + 4];
    *(float4*)&w[8] = *(const float4*)&row[xg + 8];
    float4 acc = make_float4(0.f, 0.f, 0.f, 0.f);
#pragma unroll
    for (int j = 0; j < 9; ++j) {
        float c = cf[j];
        acc.x += c * w[j];
        acc.y += c * w[j + 1];
        acc.z += c * w[j + 2];
        acc.w += c * w[j + 3];
    }
    return acc;
}

__device__ __forceinline__ float lossterm(float p, float s) {
    float sd = (s > 0.f) ? DMAXC : s;
    sd = (sd < 0.f) ? sd * ENHC : sd;
    float w = (sd < 0.f) ? (1.f + NEGWC) : 1.f;
    float d = p - sd;
    return d * d * w;
}

__global__ __launch_bounds__(256) void snake_fused(
    const float* __restrict__ pred, const float* __restrict__ snake,
    const float* __restrict__ fltr, float* __restrict__ out) {
    __shared__ float s_in[(TY + 8) * LW];   // 40x72 input halo tile
    __shared__ float s_vA[TY * LW];         // vertical dg on pred
    __shared__ float s_vB[TY * LW];         // vertical g  on pred
    __shared__ float s_wA[TY * LW];         // vertical dg on |pred|
    __shared__ float s_wB[TY * LW];         // vertical g  on |pred|
    __shared__ float s_dg[9];
    __shared__ float s_g[9];
    __shared__ float s_red[4];

    const int t = threadIdx.x;
    const int gx0 = blockIdx.x * TX;
    const int gy0 = blockIdx.y * TY;
    const int b = blockIdx.z;
    const float* img = pred + (size_t)b * (HH * WW);

    // --- separable filter recovery: dg'[i] = row-sum of f_dy; g'[j] = f_dy[0][j]/dg'[0]
    // (dg' = dg*sum(g), g' = g/sum(g); the sum(g) factors cancel in the 2D product)
    if (t < 9) {
        float s = 0.f;
#pragma unroll
        for (int j = 0; j < 9; ++j) s += fltr[t * 9 + j];
        s_dg[t] = s;
    }
    __syncthreads();
    if (t < 9) s_g[t] = fltr[t] / s_dg[0];

    // --- stage input halo tile (zero-padded at image borders)
    for (int idx = t; idx < (TY + 8) * LW; idx += 256) {
        int yy = idx / LW;
        int xx = idx - yy * LW;
        int gy = gy0 + yy - RR;
        int gx = gx0 + xx - RR;
        float v = 0.f;
        if ((unsigned)gy < HH && (unsigned)gx < WW) v = img[(size_t)gy * WW + gx];
        s_in[idx] = v;
    }
    __syncthreads();

    float dgr[9], gr[9];
#pragma unroll
    for (int i = 0; i < 9; ++i) { dgr[i] = s_dg[i]; gr[i] = s_g[i]; }

    // --- phase 1: vertical 9-tap convs, groups of 4 columns (float4 LDS ops)
    for (int gidx = t; gidx < TY * (LW / 4); gidx += 256) {
        int y = gidx / (LW / 4);
        int xg = (gidx - y * (LW / 4)) * 4;
        float4 a = make_float4(0.f, 0.f, 0.f, 0.f);
        float4 bb = a, wa = a, wb = a;
#pragma unroll
        for (int i = 0; i < 9; ++i) {
            float4 v = *(const float4*)&s_in[(y + i) * LW + xg];
            float4 av = make_float4(fabsf(v.x), fabsf(v.y), fabsf(v.z), fabsf(v.w));
            fma4(a, dgr[i], v);
            fma4(bb, gr[i], v);
            fma4(wa, dgr[i], av);
            fma4(wb, gr[i], av);
        }
        *(float4*)&s_vA[y * LW + xg] = a;
        *(float4*)&s_vB[y * LW + xg] = bb;
        *(float4*)&s_wA[y * LW + xg] = wa;
        *(float4*)&s_wB[y * LW + xg] = wb;
    }
    __syncthreads();

    // --- phase 2: horizontal convs + stores + fused loss
    float lsum = 0.f;
    float* gimg = out + 1;
    float* gimgW = out + 1 + (size_t)BB * 2 * HH * WW;
    const float* snk = snake + (size_t)b * (HH * WW);

    for (int gidx = t; gidx < TY * (TX / 4); gidx += 256) {
        int y = gidx >> 4;           // TX/4 == 16 groups per row
        int xg = (gidx & 15) * 4;
        const int ro = y * LW;
        float4 dy = hconv(&s_vA[ro], xg, gr);    // ch0: dg(y) * g(x)
        float4 dx = hconv(&s_vB[ro], xg, dgr);   // ch1: g(y) * dg(x)
        float4 dyW = hconv(&s_wA[ro], xg, gr);
        float4 dxW = hconv(&s_wB[ro], xg, dgr);

        int gy = gy0 + y, gx = gx0 + xg;
        size_t p0 = ((size_t)(b * 2 + 0)) * (HH * WW) + (size_t)gy * WW + gx;
        size_t p1 = ((size_t)(b * 2 + 1)) * (HH * WW) + (size_t)gy * WW + gx;
        // d_out+1 base is 4B-misaligned for float4 -> scalar stores (L2 merges)
        gimg[p0 + 0] = EGFC * dy.x;  gimg[p0 + 1] = EGFC * dy.y;
        gimg[p0 + 2] = EGFC * dy.z;  gimg[p0 + 3] = EGFC * dy.w;
        gimg[p1 + 0] = EGFC * dx.x;  gimg[p1 + 1] = EGFC * dx.y;
        gimg[p1 + 2] = EGFC * dx.z;  gimg[p1 + 3] = EGFC * dx.w;
        gimgW[p0 + 0] = EGFC * dyW.x; gimgW[p0 + 1] = EGFC * dyW.y;
        gimgW[p0 + 2] = EGFC * dyW.z; gimgW[p0 + 3] = EGFC * dyW.w;
        gimgW[p1 + 0] = EGFC * dxW.x; gimgW[p1 + 1] = EGFC * dxW.y;
        gimgW[p1 + 2] = EGFC * dxW.z; gimgW[p1 + 3] = EGFC * dxW.w;

        // fused loss on this block's owned pixels
        float4 pv = *(const float4*)&s_in[(y + RR) * LW + xg + RR];
        float4 sv = *(const float4*)&snk[(size_t)gy * WW + gx];
        lsum += lossterm(pv.x, sv.x) + lossterm(pv.y, sv.y) +
                lossterm(pv.z, sv.z) + lossterm(pv.w, sv.w);
    }

    // --- block reduction -> one atomicAdd per block
#pragma unroll
    for (int off = 32; off > 0; off >>= 1) lsum += __shfl_down(lsum, off);
    if ((t & 63) == 0) s_red[t >> 6] = lsum;
    __syncthreads();
    if (t == 0) {
        float tot = s_red[0] + s_red[1] + s_red[2] + s_red[3];
        atomicAdd(out, tot * (1.0f / 16777216.0f));  // /(B*H*W), exact pow2
    }
}

extern "C" void kernel_launch(void* const* d_in, const int* in_sizes, int n_in,
                              void* d_out, int out_size, void* d_ws, size_t ws_size,
                              hipStream_t stream) {
    const float* pred = (const float*)d_in[0];
    const float* snake = (const float*)d_in[1];
    const float* fltr = (const float*)d_in[2];
    float* out = (float*)d_out;

    // loss accumulator must start at 0 (d_out is poisoned before every launch)
    hipMemsetAsync(out, 0, sizeof(float), stream);

    dim3 grid(WW / TX, HH / TY, BB);
    snake_fused<<<grid, 256, 0, stream>>>(pred, snake, fltr, out);
}